// Round 2
// baseline (635.019 us; speedup 1.0000x reference)
//
#include <hip/hip_runtime.h>
#include <hip/hip_bf16.h>
#include <math.h>

typedef float f32x4 __attribute__((ext_vector_type(4)));
typedef float f32x4u __attribute__((ext_vector_type(4))) __attribute__((aligned(4)));
typedef short s16x8 __attribute__((ext_vector_type(8)));

__device__ __forceinline__ float wave_reduce64(float v) {
#pragma unroll
    for (int m = 32; m > 0; m >>= 1) v += __shfl_xor(v, m, 64);
    return v;
}

__device__ __forceinline__ unsigned short f32_to_bf16_rn(float x) {
    unsigned int u = __float_as_uint(x);
    unsigned int r = (u + 0x7fffu + ((u >> 16) & 1u)) >> 16;
    return (unsigned short)r;
}
__device__ __forceinline__ float bf16_to_f32(unsigned short h) {
    return __uint_as_float(((unsigned int)h) << 16);
}

// ---------------- Kernel A: h0, h1 (tiny MLP head) ----------------
__global__ __launch_bounds__(256) void kA(const float* __restrict__ t,
                                          const float* __restrict__ W1, const float* __restrict__ B1,
                                          const float* __restrict__ W2, const float* __restrict__ B2,
                                          float* __restrict__ h1) {
    const int tid = threadIdx.x;
    const int wave = (blockIdx.x << 2) + (tid >> 6);  // 0..1023
    const int lane = tid & 63;
    const int k = wave >> 8, n = wave & 255;
    const float ts = t[0];
    const int m0 = lane << 2;
    f32x4 w1 = *(const f32x4*)(W1 + k * 256 + m0);
    f32x4 b1 = *(const f32x4*)(B1 + k * 256 + m0);
    f32x4 w2 = *(const f32x4*)(W2 + (size_t)(k * 256 + n) * 256 + m0);
    float p = 0.f;
    p += w2.x * tanhf(w1.x * ts + b1.x);
    p += w2.y * tanhf(w1.y * ts + b1.y);
    p += w2.z * tanhf(w1.z * ts + b1.z);
    p += w2.w * tanhf(w1.w * ts + b1.w);
    p = wave_reduce64(p);
    if (lane == 0) h1[k * 256 + n] = tanhf(p + B2[k * 256 + n]);
}

// ---------------- Kernel B: the 540 MB stream ----------------
// 4 rows per wave-iteration: 4 independent 16B/lane loads in flight + 4 interleaved
// butterfly reduce chains. h-vectors hoisted out of the loop. Segment boundaries are
// all multiples of 4, so a 4-row group never straddles segments.
__global__ __launch_bounds__(256) void kB(const float* __restrict__ Wwin, const float* __restrict__ bwin,
                                          const float* __restrict__ Wwout, const float* __restrict__ bwout,
                                          const float* __restrict__ Wb, const float* __restrict__ bb,
                                          const float* __restrict__ Wg, const float* __restrict__ bg,
                                          const float* __restrict__ h1,
                                          float* __restrict__ w_in, float* __restrict__ w_out,
                                          unsigned short* __restrict__ w_in_hi, unsigned short* __restrict__ w_in_lo,
                                          unsigned short* __restrict__ w_out_t,
                                          float* __restrict__ b_arr, float* __restrict__ gate) {
    const int lane = threadIdx.x & 63;
    const int wave0 = (blockIdx.x << 2) + (threadIdx.x >> 6);
    const int nwaves = gridDim.x << 2;
    const int m0 = lane << 2;
    const f32x4 h_win  = *(const f32x4*)(h1 + m0);
    const f32x4 h_wout = *(const f32x4*)(h1 + 256 + m0);
    const f32x4 h_b    = *(const f32x4*)(h1 + 512 + m0);
    const f32x4 h_g    = *(const f32x4*)(h1 + 768 + m0);
    for (int g = wave0; g < 132096; g += nwaves) {
        const int r = g << 2;
        const float* W; const float* bias; f32x4 hv; int idx, seg;
        if (r < 262144)      { seg = 0; idx = r;          W = Wwin;  bias = bwin;  hv = h_win; }
        else if (r < 524288) { seg = 1; idx = r - 262144; W = Wwout; bias = bwout; hv = h_wout; }
        else if (r < 526336) { seg = 2; idx = r - 524288; W = Wb;    bias = bb;    hv = h_b; }
        else                 { seg = 3; idx = r - 526336; W = Wg;    bias = bg;    hv = h_g; }
        const float* base = W + (size_t)idx * 256 + m0;
        f32x4 w0 = *(const f32x4*)(base);
        f32x4 w1 = *(const f32x4*)(base + 256);
        f32x4 w2 = *(const f32x4*)(base + 512);
        f32x4 w3 = *(const f32x4*)(base + 768);
        float p0 = w0.x * hv.x + w0.y * hv.y + w0.z * hv.z + w0.w * hv.w;
        float p1 = w1.x * hv.x + w1.y * hv.y + w1.z * hv.z + w1.w * hv.w;
        float p2 = w2.x * hv.x + w2.y * hv.y + w2.z * hv.z + w2.w * hv.w;
        float p3 = w3.x * hv.x + w3.y * hv.y + w3.z * hv.z + w3.w * hv.w;
#pragma unroll
        for (int m = 32; m > 0; m >>= 1) {
            p0 += __shfl_xor(p0, m, 64);
            p1 += __shfl_xor(p1, m, 64);
            p2 += __shfl_xor(p2, m, 64);
            p3 += __shfl_xor(p3, m, 64);
        }
        if (lane < 4) {
            float v = (lane == 0) ? p0 : (lane == 1) ? p1 : (lane == 2) ? p2 : p3;
            const int id2 = idx + lane;
            v += bias[id2];
            if (seg == 0) {
                w_in[id2] = v;
                unsigned short hi = f32_to_bf16_rn(v);
                w_in_hi[id2] = hi;
                w_in_lo[id2] = f32_to_bf16_rn(v - bf16_to_f32(hi));
            } else if (seg == 1) {
                w_out[id2] = v;
                w_out_t[(size_t)(id2 & 127) * 2048 + (id2 >> 7)] = f32_to_bf16_rn(v);
            } else if (seg == 2) {
                b_arr[id2] = v;
            } else {
                gate[id2] = 1.f / (1.f + __expf(-v));
            }
        }
    }
}

// ---------------- Kernel C: s[f] = dot(w_in[f,:], w_out[f,:]) ----------------
__global__ __launch_bounds__(256) void kC(const float* __restrict__ w_in, const float* __restrict__ w_out,
                                          float* __restrict__ s) {
    const int f = (blockIdx.x << 2) + (threadIdx.x >> 6);
    const int lane = threadIdx.x & 63;
    float2 a = *(const float2*)(w_in + (size_t)f * 128 + lane * 2);
    float2 b = *(const float2*)(w_out + (size_t)f * 128 + lane * 2);
    float p = a.x * b.x + a.y * b.y;
    p = wave_reduce64(p);
    if (lane == 0) s[f] = p;
}

// ---------------- Kernel D: fused h/g/dz/trace via MFMA ----------------
// 512 blocks x 256 thr (2 blocks/CU, 8 waves/CU). Block owns 16 batch rows; the 4
// waves are a 4-way K-split over f (512 f's each = 8 chunks of 64), merged via LDS.
// GEMM1 (K=128): split-bf16 hi/lo (3 MFMAs) for ~fp32 precision. GEMM2: straight bf16.
__global__ __launch_bounds__(256) void kD(const float* __restrict__ zin,
                                          const unsigned short* __restrict__ w_in_hi,
                                          const unsigned short* __restrict__ w_in_lo,
                                          const unsigned short* __restrict__ w_out_t,
                                          const float* __restrict__ b_arr, const float* __restrict__ gate,
                                          const float* __restrict__ s, float* __restrict__ out) {
    __shared__ __attribute__((aligned(16))) unsigned short g_lds[4][16][72];  // per-wave g staging
    __shared__ __attribute__((aligned(16))) float red[3][64][36];             // K-split merge

    const int tid = threadIdx.x;
    const int w = tid >> 6, lane = tid & 63;
    const int q = lane >> 4, lm = lane & 15;
    const int b0 = blockIdx.x * 16;
    const int brow = b0 + lm;

    // z A-fragments (persistent): 4 k-tiles of K=128, split hi/lo
    s16x8 zh[4], zl[4];
#pragma unroll
    for (int kt = 0; kt < 4; kt++) {
        const float* zp = zin + (size_t)brow * 129 + kt * 32 + q * 8;
        f32x4u z0 = *(const f32x4u*)(zp);
        f32x4u z1 = *(const f32x4u*)(zp + 4);
        float zv[8] = {z0.x, z0.y, z0.z, z0.w, z1.x, z1.y, z1.z, z1.w};
#pragma unroll
        for (int j = 0; j < 8; j++) {
            unsigned short hi = f32_to_bf16_rn(zv[j]);
            zh[kt][j] = (short)hi;
            zl[kt][j] = (short)f32_to_bf16_rn(zv[j] - bf16_to_f32(hi));
        }
    }

    f32x4 acc2[8];
#pragma unroll
    for (int ct = 0; ct < 8; ct++) acc2[ct] = (f32x4){0.f, 0.f, 0.f, 0.f};
    float tr[4] = {0.f, 0.f, 0.f, 0.f};

    for (int ch = 0; ch < 8; ch++) {
        const int f0 = w * 512 + ch * 64;
#pragma unroll
        for (int nt = 0; nt < 4; nt++) {
            const int fc = f0 + nt * 16 + lm;
            const unsigned short* ph = w_in_hi + (size_t)fc * 128;
            const unsigned short* pl = w_in_lo + (size_t)fc * 128;
            f32x4 acc1 = {0.f, 0.f, 0.f, 0.f};
#pragma unroll
            for (int kt = 0; kt < 4; kt++) {
                s16x8 bh = *(const s16x8*)(ph + kt * 32 + q * 8);
                s16x8 bl = *(const s16x8*)(pl + kt * 32 + q * 8);
                acc1 = __builtin_amdgcn_mfma_f32_16x16x32_bf16(zh[kt], bh, acc1, 0, 0, 0);
                acc1 = __builtin_amdgcn_mfma_f32_16x16x32_bf16(zh[kt], bl, acc1, 0, 0, 0);
                acc1 = __builtin_amdgcn_mfma_f32_16x16x32_bf16(zl[kt], bh, acc1, 0, 0, 0);
            }
            const float gv = gate[fc], bv = b_arr[fc], sv = s[fc];
#pragma unroll
            for (int i = 0; i < 4; i++) {
                float pre = acc1[i] + bv;
                float e = __expf(2.f * pre);
                float th = 1.f - 2.f * __builtin_amdgcn_rcpf(e + 1.f);
                float g = th * gv;
                tr[i] += (1.f - th * th) * gv * sv;
                g_lds[w][q * 4 + i][nt * 16 + lm] = f32_to_bf16_rn(g);
            }
        }
#pragma unroll
        for (int kt2 = 0; kt2 < 2; kt2++) {
            s16x8 af = *(const s16x8*)&g_lds[w][lm][kt2 * 32 + q * 8];
#pragma unroll
            for (int ct = 0; ct < 8; ct++) {
                s16x8 bf = *(const s16x8*)(w_out_t + (size_t)(ct * 16 + lm) * 2048 + f0 + kt2 * 32 + q * 8);
                acc2[ct] = __builtin_amdgcn_mfma_f32_16x16x32_bf16(af, bf, acc2[ct], 0, 0, 0);
            }
        }
    }

    // merge 4-way K-split
    if (w != 0) {
#pragma unroll
        for (int ct = 0; ct < 8; ct++) *(f32x4*)&red[w - 1][lane][ct * 4] = acc2[ct];
        *(f32x4*)&red[w - 1][lane][32] = (f32x4){tr[0], tr[1], tr[2], tr[3]};
    }
    __syncthreads();
    if (w == 0) {
#pragma unroll
        for (int ww = 0; ww < 3; ww++) {
#pragma unroll
            for (int ct = 0; ct < 8; ct++) {
                f32x4 o = *(const f32x4*)&red[ww][lane][ct * 4];
                acc2[ct].x += o.x; acc2[ct].y += o.y; acc2[ct].z += o.z; acc2[ct].w += o.w;
            }
            f32x4 to = *(const f32x4*)&red[ww][lane][32];
            tr[0] += to.x; tr[1] += to.y; tr[2] += to.z; tr[3] += to.w;
        }

        const float inv = 1.f / 2048.f;
#pragma unroll
        for (int ct = 0; ct < 8; ct++)
#pragma unroll
            for (int i = 0; i < 4; i++)
                out[(size_t)(b0 + q * 4 + i) * 129 + ct * 16 + lm] = acc2[ct][i] * inv;
#pragma unroll
        for (int i = 0; i < 4; i++) {
            float t2 = tr[i];
            t2 += __shfl_xor(t2, 1, 64);
            t2 += __shfl_xor(t2, 2, 64);
            t2 += __shfl_xor(t2, 4, 64);
            t2 += __shfl_xor(t2, 8, 64);
            if (lm == 0) out[(size_t)(b0 + q * 4 + i) * 129 + 128] = -t2 * inv;
        }
    }
}

extern "C" void kernel_launch(void* const* d_in, const int* in_sizes, int n_in,
                              void* d_out, int out_size, void* d_ws, size_t ws_size,
                              hipStream_t stream) {
    const float* t     = (const float*)d_in[0];
    const float* z     = (const float*)d_in[1];
    const float* W1    = (const float*)d_in[2];
    const float* B1    = (const float*)d_in[3];
    const float* W2    = (const float*)d_in[4];
    const float* B2    = (const float*)d_in[5];
    const float* W3win = (const float*)d_in[6];
    const float* b3win = (const float*)d_in[7];
    const float* W3wo  = (const float*)d_in[8];
    const float* b3wo  = (const float*)d_in[9];
    const float* W3b   = (const float*)d_in[10];
    const float* b3b   = (const float*)d_in[11];
    const float* W3g   = (const float*)d_in[12];
    const float* b3g   = (const float*)d_in[13];
    float* out = (float*)d_out;

    float* h1    = (float*)d_ws;        // 1024
    float* w_in  = h1 + 1024;           // 262144
    float* w_out = w_in + 262144;       // 262144
    float* b_arr = w_out + 262144;      // 2048
    float* gate  = b_arr + 2048;        // 2048
    float* s     = gate + 2048;         // 2048
    unsigned short* w_in_hi = (unsigned short*)(s + 2048);  // 262144
    unsigned short* w_in_lo = w_in_hi + 262144;             // 262144
    unsigned short* w_out_t = w_in_lo + 262144;             // 262144

    kA<<<256, 256, 0, stream>>>(t, W1, B1, W2, B2, h1);
    kB<<<2048, 256, 0, stream>>>(W3win, b3win, W3wo, b3wo, W3b, b3b, W3g, b3g, h1,
                                 w_in, w_out, w_in_hi, w_in_lo, w_out_t, b_arr, gate);
    kC<<<512, 256, 0, stream>>>(w_in, w_out, s);
    kD<<<512, 256, 0, stream>>>(z, w_in_hi, w_in_lo, w_out_t, b_arr, gate, s, out);
    (void)in_sizes; (void)n_in; (void)out_size; (void)ws_size;
}

// Round 3
// 624.004 us; speedup vs baseline: 1.0177x; 1.0177x over previous
//
#include <hip/hip_runtime.h>
#include <hip/hip_bf16.h>
#include <math.h>

typedef float f32x4 __attribute__((ext_vector_type(4)));
typedef float f32x4u __attribute__((ext_vector_type(4))) __attribute__((aligned(4)));
typedef short s16x8 __attribute__((ext_vector_type(8)));

__device__ __forceinline__ float wave_reduce64(float v) {
#pragma unroll
    for (int m = 32; m > 0; m >>= 1) v += __shfl_xor(v, m, 64);
    return v;
}

__device__ __forceinline__ unsigned short f32_to_bf16_rn(float x) {
    unsigned int u = __float_as_uint(x);
    unsigned int r = (u + 0x7fffu + ((u >> 16) & 1u)) >> 16;
    return (unsigned short)r;
}
__device__ __forceinline__ float bf16_to_f32(unsigned short h) {
    return __uint_as_float(((unsigned int)h) << 16);
}

__device__ __forceinline__ void dma_row16(const float* gsrc, float* ldst) {
    // 64 lanes x 16B -> one contiguous 1KB LDS row at wave-uniform ldst
    __builtin_amdgcn_global_load_lds(
        (const __attribute__((address_space(1))) unsigned int*)gsrc,
        (__attribute__((address_space(3))) unsigned int*)ldst,
        16, 0, 0);
}

// ---------------- Kernel A: h0, h1 (tiny MLP head) ----------------
__global__ __launch_bounds__(256) void kA(const float* __restrict__ t,
                                          const float* __restrict__ W1, const float* __restrict__ B1,
                                          const float* __restrict__ W2, const float* __restrict__ B2,
                                          float* __restrict__ h1) {
    const int tid = threadIdx.x;
    const int wave = (blockIdx.x << 2) + (tid >> 6);
    const int lane = tid & 63;
    const int k = wave >> 8, n = wave & 255;
    const float ts = t[0];
    const int m0 = lane << 2;
    f32x4 w1 = *(const f32x4*)(W1 + k * 256 + m0);
    f32x4 b1 = *(const f32x4*)(B1 + k * 256 + m0);
    f32x4 w2 = *(const f32x4*)(W2 + (size_t)(k * 256 + n) * 256 + m0);
    float p = 0.f;
    p += w2.x * tanhf(w1.x * ts + b1.x);
    p += w2.y * tanhf(w1.y * ts + b1.y);
    p += w2.z * tanhf(w1.z * ts + b1.z);
    p += w2.w * tanhf(w1.w * ts + b1.w);
    p = wave_reduce64(p);
    if (lane == 0) h1[k * 256 + n] = tanhf(p + B2[k * 256 + n]);
}

// ---------------- Kernel B (DMA version): the 540 MB stream ----------------
// 256 persistent blocks (1/CU), 4 waves. Chunk = 64 rows (16/wave), wave-private
// double-buffered LDS (stride 260 words for bank stagger), global_load_lds DMA,
// explicit vmcnt(16) pipelining, NO barriers in the loop.
// Chunk segments (chunk=64 rows): [0,4096)=w_in [4096,8192)=w_out [8192,8224)=b [8224,8256)=gate
__global__ __launch_bounds__(256) void kB_dma(const float* __restrict__ Wwin, const float* __restrict__ bwin,
                                              const float* __restrict__ Wwout, const float* __restrict__ bwout,
                                              const float* __restrict__ Wb, const float* __restrict__ bb,
                                              const float* __restrict__ Wg, const float* __restrict__ bg,
                                              const float* __restrict__ h1,
                                              float* __restrict__ w_in, float* __restrict__ w_out,
                                              unsigned short* __restrict__ w_in_hi, unsigned short* __restrict__ w_in_lo,
                                              unsigned short* __restrict__ w_out_t,
                                              float* __restrict__ b_arr, float* __restrict__ gate) {
    extern __shared__ float smem[];  // [0,1088): padded h; [1088, 1088+8*16*260): row buffers
    float* h_s = smem;
    float* bufs = smem + 1088;

    const int tid = threadIdx.x;
    const int w = tid >> 6, lane = tid & 63;

    // stage h with 68-word padded quarters (conflict-free broadcast reads later)
    {
        const int seg = tid >> 6, q = (tid >> 4) & 3, i = tid & 15;
        f32x4 hv = *(const f32x4*)(h1 + seg * 256 + q * 64 + i * 4);
        *(f32x4*)(h_s + seg * 272 + q * 68 + i * 4) = hv;
    }

    const int r = lane >> 2, c = lane & 3;

    // prologue: issue chunks k=0 (buf0) and k=1 (buf1)
#pragma unroll
    for (int pk = 0; pk < 2; pk++) {
        const int ci = blockIdx.x + pk * 256;
        const float* W; int row0;
        if (ci < 4096)      { W = Wwin;  row0 = ci * 64; }
        else if (ci < 8192) { W = Wwout; row0 = (ci - 4096) * 64; }
        else if (ci < 8224) { W = Wb;    row0 = (ci - 8192) * 64; }
        else                { W = Wg;    row0 = (ci - 8224) * 64; }
        const float* src = W + (size_t)(row0 + w * 16) * 256 + (lane << 2);
        float* dst = bufs + (size_t)((pk * 4 + w) * 16) * 260;
#pragma unroll
        for (int rr = 0; rr < 16; rr++) dma_row16(src + rr * 256, dst + rr * 260);
    }

    __syncthreads();  // h ready (also drains prologue DMAs once; harmless)

    for (int k = 0;; k++) {
        const int cur = blockIdx.x + k * 256;
        if (cur >= 8256) break;
        const int buf = k & 1;
        const bool has_next = (cur + 256) < 8256;
        if (has_next) asm volatile("s_waitcnt vmcnt(16)" ::: "memory");
        else          asm volatile("s_waitcnt vmcnt(0)" ::: "memory");

        int seg, row0;
        const float* bias;
        if (cur < 4096)      { seg = 0; row0 = cur * 64;          bias = bwin; }
        else if (cur < 8192) { seg = 1; row0 = (cur - 4096) * 64; bias = bwout; }
        else if (cur < 8224) { seg = 2; row0 = (cur - 8192) * 64; bias = bb; }
        else                 { seg = 3; row0 = (cur - 8224) * 64; bias = bg; }

        const float* rowp = bufs + (size_t)((buf * 4 + w) * 16 + r) * 260 + c * 64;
        const float* hp = h_s + seg * 272 + c * 68;
        float a0 = 0.f, a1 = 0.f;
#pragma unroll
        for (int j = 0; j < 16; j += 2) {
            f32x4 d0 = *(const f32x4*)(rowp + 4 * j);
            f32x4 h0 = *(const f32x4*)(hp + 4 * j);
            f32x4 d1 = *(const f32x4*)(rowp + 4 * j + 4);
            f32x4 h1v = *(const f32x4*)(hp + 4 * j + 4);
            a0 += d0.x * h0.x + d0.y * h0.y + d0.z * h0.z + d0.w * h0.w;
            a1 += d1.x * h1v.x + d1.y * h1v.y + d1.z * h1v.z + d1.w * h1v.w;
        }
        float acc = a0 + a1;
        acc += __shfl_xor(acc, 1, 64);
        acc += __shfl_xor(acc, 2, 64);

        if (c == 0) {
            const int idx = row0 + w * 16 + r;
            float v = acc + bias[idx];
            if (seg == 0) {
                w_in[idx] = v;
                unsigned short hi = f32_to_bf16_rn(v);
                w_in_hi[idx] = hi;
                w_in_lo[idx] = f32_to_bf16_rn(v - bf16_to_f32(hi));
            } else if (seg == 1) {
                w_out[idx] = v;
                w_out_t[(size_t)(idx & 127) * 2048 + (idx >> 7)] = f32_to_bf16_rn(v);
            } else if (seg == 2) {
                b_arr[idx] = v;
            } else {
                gate[idx] = 1.f / (1.f + __expf(-v));
            }
        }

        // make sure our LDS reads of this buffer completed before overwriting it
        asm volatile("s_waitcnt lgkmcnt(0)" ::: "memory");

        const int pf = cur + 512;
        if (pf < 8256) {
            const float* W; int prow0;
            if (pf < 4096)      { W = Wwin;  prow0 = pf * 64; }
            else if (pf < 8192) { W = Wwout; prow0 = (pf - 4096) * 64; }
            else if (pf < 8224) { W = Wb;    prow0 = (pf - 8192) * 64; }
            else                { W = Wg;    prow0 = (pf - 8224) * 64; }
            const float* src = W + (size_t)(prow0 + w * 16) * 256 + (lane << 2);
            float* dst = bufs + (size_t)((buf * 4 + w) * 16) * 260;
#pragma unroll
            for (int rr = 0; rr < 16; rr++) dma_row16(src + rr * 256, dst + rr * 260);
        }
    }
}

// ---------------- Kernel B fallback (round-2 structure) ----------------
__global__ __launch_bounds__(256) void kB_fb(const float* __restrict__ Wwin, const float* __restrict__ bwin,
                                             const float* __restrict__ Wwout, const float* __restrict__ bwout,
                                             const float* __restrict__ Wb, const float* __restrict__ bb,
                                             const float* __restrict__ Wg, const float* __restrict__ bg,
                                             const float* __restrict__ h1,
                                             float* __restrict__ w_in, float* __restrict__ w_out,
                                             unsigned short* __restrict__ w_in_hi, unsigned short* __restrict__ w_in_lo,
                                             unsigned short* __restrict__ w_out_t,
                                             float* __restrict__ b_arr, float* __restrict__ gate) {
    const int lane = threadIdx.x & 63;
    const int wave0 = (blockIdx.x << 2) + (threadIdx.x >> 6);
    const int nwaves = gridDim.x << 2;
    const int m0 = lane << 2;
    const f32x4 h_win  = *(const f32x4*)(h1 + m0);
    const f32x4 h_wout = *(const f32x4*)(h1 + 256 + m0);
    const f32x4 h_b    = *(const f32x4*)(h1 + 512 + m0);
    const f32x4 h_g    = *(const f32x4*)(h1 + 768 + m0);
    for (int g = wave0; g < 132096; g += nwaves) {
        const int rr = g << 2;
        const float* W; const float* bias; f32x4 hv; int idx, seg;
        if (rr < 262144)      { seg = 0; idx = rr;          W = Wwin;  bias = bwin;  hv = h_win; }
        else if (rr < 524288) { seg = 1; idx = rr - 262144; W = Wwout; bias = bwout; hv = h_wout; }
        else if (rr < 526336) { seg = 2; idx = rr - 524288; W = Wb;    bias = bb;    hv = h_b; }
        else                  { seg = 3; idx = rr - 526336; W = Wg;    bias = bg;    hv = h_g; }
        const float* base = W + (size_t)idx * 256 + m0;
        f32x4 w0 = *(const f32x4*)(base);
        f32x4 w1 = *(const f32x4*)(base + 256);
        f32x4 w2 = *(const f32x4*)(base + 512);
        f32x4 w3 = *(const f32x4*)(base + 768);
        float p0 = w0.x * hv.x + w0.y * hv.y + w0.z * hv.z + w0.w * hv.w;
        float p1 = w1.x * hv.x + w1.y * hv.y + w1.z * hv.z + w1.w * hv.w;
        float p2 = w2.x * hv.x + w2.y * hv.y + w2.z * hv.z + w2.w * hv.w;
        float p3 = w3.x * hv.x + w3.y * hv.y + w3.z * hv.z + w3.w * hv.w;
#pragma unroll
        for (int m = 32; m > 0; m >>= 1) {
            p0 += __shfl_xor(p0, m, 64);
            p1 += __shfl_xor(p1, m, 64);
            p2 += __shfl_xor(p2, m, 64);
            p3 += __shfl_xor(p3, m, 64);
        }
        if (lane < 4) {
            float v = (lane == 0) ? p0 : (lane == 1) ? p1 : (lane == 2) ? p2 : p3;
            const int id2 = idx + lane;
            v += bias[id2];
            if (seg == 0) {
                w_in[id2] = v;
                unsigned short hi = f32_to_bf16_rn(v);
                w_in_hi[id2] = hi;
                w_in_lo[id2] = f32_to_bf16_rn(v - bf16_to_f32(hi));
            } else if (seg == 1) {
                w_out[id2] = v;
                w_out_t[(size_t)(id2 & 127) * 2048 + (id2 >> 7)] = f32_to_bf16_rn(v);
            } else if (seg == 2) {
                b_arr[id2] = v;
            } else {
                gate[id2] = 1.f / (1.f + __expf(-v));
            }
        }
    }
}

// ---------------- Kernel C: s[f] = dot(w_in[f,:], w_out[f,:]) ----------------
__global__ __launch_bounds__(256) void kC(const float* __restrict__ w_in, const float* __restrict__ w_out,
                                          float* __restrict__ s) {
    const int f = (blockIdx.x << 2) + (threadIdx.x >> 6);
    const int lane = threadIdx.x & 63;
    float2 a = *(const float2*)(w_in + (size_t)f * 128 + lane * 2);
    float2 b = *(const float2*)(w_out + (size_t)f * 128 + lane * 2);
    float p = a.x * b.x + a.y * b.y;
    p = wave_reduce64(p);
    if (lane == 0) s[f] = p;
}

// ---------------- Kernel D: fused h/g/dz/trace via MFMA (unchanged, known-good) ----------------
__global__ __launch_bounds__(256) void kD(const float* __restrict__ zin,
                                          const unsigned short* __restrict__ w_in_hi,
                                          const unsigned short* __restrict__ w_in_lo,
                                          const unsigned short* __restrict__ w_out_t,
                                          const float* __restrict__ b_arr, const float* __restrict__ gate,
                                          const float* __restrict__ s, float* __restrict__ out) {
    __shared__ __attribute__((aligned(16))) unsigned short g_lds[4][16][72];
    __shared__ __attribute__((aligned(16))) float red[3][64][36];

    const int tid = threadIdx.x;
    const int w = tid >> 6, lane = tid & 63;
    const int q = lane >> 4, lm = lane & 15;
    const int b0 = blockIdx.x * 16;
    const int brow = b0 + lm;

    s16x8 zh[4], zl[4];
#pragma unroll
    for (int kt = 0; kt < 4; kt++) {
        const float* zp = zin + (size_t)brow * 129 + kt * 32 + q * 8;
        f32x4u z0 = *(const f32x4u*)(zp);
        f32x4u z1 = *(const f32x4u*)(zp + 4);
        float zv[8] = {z0.x, z0.y, z0.z, z0.w, z1.x, z1.y, z1.z, z1.w};
#pragma unroll
        for (int j = 0; j < 8; j++) {
            unsigned short hi = f32_to_bf16_rn(zv[j]);
            zh[kt][j] = (short)hi;
            zl[kt][j] = (short)f32_to_bf16_rn(zv[j] - bf16_to_f32(hi));
        }
    }

    f32x4 acc2[8];
#pragma unroll
    for (int ct = 0; ct < 8; ct++) acc2[ct] = (f32x4){0.f, 0.f, 0.f, 0.f};
    float tr[4] = {0.f, 0.f, 0.f, 0.f};

    for (int ch = 0; ch < 8; ch++) {
        const int f0 = w * 512 + ch * 64;
#pragma unroll
        for (int nt = 0; nt < 4; nt++) {
            const int fc = f0 + nt * 16 + lm;
            const unsigned short* ph = w_in_hi + (size_t)fc * 128;
            const unsigned short* pl = w_in_lo + (size_t)fc * 128;
            f32x4 acc1 = {0.f, 0.f, 0.f, 0.f};
#pragma unroll
            for (int kt = 0; kt < 4; kt++) {
                s16x8 bh = *(const s16x8*)(ph + kt * 32 + q * 8);
                s16x8 bl = *(const s16x8*)(pl + kt * 32 + q * 8);
                acc1 = __builtin_amdgcn_mfma_f32_16x16x32_bf16(zh[kt], bh, acc1, 0, 0, 0);
                acc1 = __builtin_amdgcn_mfma_f32_16x16x32_bf16(zh[kt], bl, acc1, 0, 0, 0);
                acc1 = __builtin_amdgcn_mfma_f32_16x16x32_bf16(zl[kt], bh, acc1, 0, 0, 0);
            }
            const float gv = gate[fc], bv = b_arr[fc], sv = s[fc];
#pragma unroll
            for (int i = 0; i < 4; i++) {
                float pre = acc1[i] + bv;
                float e = __expf(2.f * pre);
                float th = 1.f - 2.f * __builtin_amdgcn_rcpf(e + 1.f);
                float g = th * gv;
                tr[i] += (1.f - th * th) * gv * sv;
                g_lds[w][q * 4 + i][nt * 16 + lm] = f32_to_bf16_rn(g);
            }
        }
#pragma unroll
        for (int kt2 = 0; kt2 < 2; kt2++) {
            s16x8 af = *(const s16x8*)&g_lds[w][lm][kt2 * 32 + q * 8];
#pragma unroll
            for (int ct = 0; ct < 8; ct++) {
                s16x8 bf = *(const s16x8*)(w_out_t + (size_t)(ct * 16 + lm) * 2048 + f0 + kt2 * 32 + q * 8);
                acc2[ct] = __builtin_amdgcn_mfma_f32_16x16x32_bf16(af, bf, acc2[ct], 0, 0, 0);
            }
        }
    }

    if (w != 0) {
#pragma unroll
        for (int ct = 0; ct < 8; ct++) *(f32x4*)&red[w - 1][lane][ct * 4] = acc2[ct];
        *(f32x4*)&red[w - 1][lane][32] = (f32x4){tr[0], tr[1], tr[2], tr[3]};
    }
    __syncthreads();
    if (w == 0) {
#pragma unroll
        for (int ww = 0; ww < 3; ww++) {
#pragma unroll
            for (int ct = 0; ct < 8; ct++) {
                f32x4 o = *(const f32x4*)&red[ww][lane][ct * 4];
                acc2[ct].x += o.x; acc2[ct].y += o.y; acc2[ct].z += o.z; acc2[ct].w += o.w;
            }
            f32x4 to = *(const f32x4*)&red[ww][lane][32];
            tr[0] += to.x; tr[1] += to.y; tr[2] += to.z; tr[3] += to.w;
        }

        const float inv = 1.f / 2048.f;
#pragma unroll
        for (int ct = 0; ct < 8; ct++)
#pragma unroll
            for (int i = 0; i < 4; i++)
                out[(size_t)(b0 + q * 4 + i) * 129 + ct * 16 + lm] = acc2[ct][i] * inv;
#pragma unroll
        for (int i = 0; i < 4; i++) {
            float t2 = tr[i];
            t2 += __shfl_xor(t2, 1, 64);
            t2 += __shfl_xor(t2, 2, 64);
            t2 += __shfl_xor(t2, 4, 64);
            t2 += __shfl_xor(t2, 8, 64);
            if (lm == 0) out[(size_t)(b0 + q * 4 + i) * 129 + 128] = -t2 * inv;
        }
    }
}

extern "C" void kernel_launch(void* const* d_in, const int* in_sizes, int n_in,
                              void* d_out, int out_size, void* d_ws, size_t ws_size,
                              hipStream_t stream) {
    const float* t     = (const float*)d_in[0];
    const float* z     = (const float*)d_in[1];
    const float* W1    = (const float*)d_in[2];
    const float* B1    = (const float*)d_in[3];
    const float* W2    = (const float*)d_in[4];
    const float* B2    = (const float*)d_in[5];
    const float* W3win = (const float*)d_in[6];
    const float* b3win = (const float*)d_in[7];
    const float* W3wo  = (const float*)d_in[8];
    const float* b3wo  = (const float*)d_in[9];
    const float* W3b   = (const float*)d_in[10];
    const float* b3b   = (const float*)d_in[11];
    const float* W3g   = (const float*)d_in[12];
    const float* b3g   = (const float*)d_in[13];
    float* out = (float*)d_out;

    float* h1    = (float*)d_ws;        // 1024
    float* w_in  = h1 + 1024;           // 262144
    float* w_out = w_in + 262144;       // 262144
    float* b_arr = w_out + 262144;      // 2048
    float* gate  = b_arr + 2048;        // 2048
    float* s     = gate + 2048;         // 2048
    unsigned short* w_in_hi = (unsigned short*)(s + 2048);  // 262144
    unsigned short* w_in_lo = w_in_hi + 262144;             // 262144
    unsigned short* w_out_t = w_in_lo + 262144;             // 262144

    kA<<<256, 256, 0, stream>>>(t, W1, B1, W2, B2, h1);

    const int kb_lds = (1088 + 8 * 16 * 260) * 4;  // 137,472 B
    hipError_t attr_ok = hipFuncSetAttribute((const void*)kB_dma,
                                             hipFuncAttributeMaxDynamicSharedMemorySize, kb_lds);
    if (attr_ok == hipSuccess) {
        kB_dma<<<256, 256, kb_lds, stream>>>(W3win, b3win, W3wo, b3wo, W3b, b3b, W3g, b3g, h1,
                                             w_in, w_out, w_in_hi, w_in_lo, w_out_t, b_arr, gate);
    } else {
        kB_fb<<<2048, 256, 0, stream>>>(W3win, b3win, W3wo, b3wo, W3b, b3b, W3g, b3g, h1,
                                        w_in, w_out, w_in_hi, w_in_lo, w_out_t, b_arr, gate);
    }
    kC<<<512, 256, 0, stream>>>(w_in, w_out, s);
    kD<<<512, 256, 0, stream>>>(z, w_in_hi, w_in_lo, w_out_t, b_arr, gate, s, out);
    (void)in_sizes; (void)n_in; (void)out_size; (void)ws_size;
}